// Round 1
// baseline (735.693 us; speedup 1.0000x reference)
//
#include <hip/hip_runtime.h>
#include <math.h>

#define D 256
#define K 1024
#define N_PTS 65536            // 64 * 32 * 32
#define BETA 0.25f
#define ORTHO_L 10.0f

#define OUT_ELEMS 16777216     // 64*256*32*32
#define LOSS_OFF 16777216
#define IDX_OFF  16777217

// ws float layout
#define WS_SSE_VQ    0
#define WS_SSE_ORTHO 1
#define WS_B         2            // 1024 floats: ||e_k||^2
#define WS_NORM      (2 + 1024)   // 1024 floats: ||e_k||

// ---------------- kernel 1: per-code squared norms ----------------
__global__ __launch_bounds__(64) void codes_kernel(const float* __restrict__ w,
                                                   float* __restrict__ ws) {
    int k = blockIdx.x;
    int lane = threadIdx.x;                       // 0..63
    float4 v = *(const float4*)(w + (size_t)k * D + lane * 4);
    float s = v.x * v.x + v.y * v.y + v.z * v.z + v.w * v.w;
    for (int m = 32; m; m >>= 1) s += __shfl_xor(s, m, 64);
    if (lane == 0) {
        ws[WS_B + k] = s;
        ws[WS_NORM + k] = sqrtf(s);
    }
}

// ---------------- kernel 2: fused distance-GEMM + argmin ----------------
#define MT 32    // points per block
#define NT 128   // codes per k-chunk
#define DC 32    // d per W stage

__global__ __launch_bounds__(256) void argmin_kernel(const float* __restrict__ x,
                                                     const float* __restrict__ w,
                                                     const float* __restrict__ ws,
                                                     float* __restrict__ out_idx) {
    __shared__ float Xs[D][MT];       // 32 KB, d-major
    __shared__ float Ws[DC][NT];      // 16 KB, d-major
    __shared__ float Apart[8][MT];
    __shared__ float Ash[MT];

    int tid = threadIdx.x;
    int tx = tid & 31;                // code group 0..31
    int ty = tid >> 5;                // point group 0..7

    int n0 = blockIdx.x * MT;
    int b  = n0 >> 10;                // 1024 points per batch image
    int hw0 = n0 & 1023;

    // ---- stage X tile [32 pts][256 d] transposed into Xs[d][p] ----
    const float* xb = x + (size_t)b * (D * 1024) + hw0;
    {
        int p = tid & 31;
        int cq = tid >> 5;            // 8 channels per pass
        for (int c0 = 0; c0 < D; c0 += 8) {
            int c = c0 + cq;
            Xs[c][p] = xb[(size_t)c * 1024 + p];
        }
    }
    __syncthreads();

    // ---- A_n = sum_d x^2 (per-point) ----
    {
        int p = tid & 31;
        int q = tid >> 5;
        float s = 0.f;
        #pragma unroll
        for (int d = 0; d < 32; ++d) {
            float v = Xs[q * 32 + d][p];
            s += v * v;
        }
        Apart[q][p] = s;
    }
    __syncthreads();
    if (tid < MT) {
        float s = 0.f;
        #pragma unroll
        for (int q = 0; q < 8; ++q) s += Apart[q][tid];
        Ash[tid] = s;
    }
    __syncthreads();

    float bestv[4];
    int   besti[4];
    #pragma unroll
    for (int i = 0; i < 4; ++i) { bestv[i] = 3.4e38f; besti[i] = 0; }

    for (int kc = 0; kc < K / NT; ++kc) {
        float acc[4][4];
        #pragma unroll
        for (int i = 0; i < 4; ++i)
            #pragma unroll
            for (int j = 0; j < 4; ++j) acc[i][j] = 0.f;

        for (int dc = 0; dc < D / DC; ++dc) {
            // issue global loads for W chunk: 128 codes x 32 d
            int r = tid >> 1;                   // code 0..127
            int dbase = (tid & 1) << 4;         // 0 or 16
            const float* wr = w + (size_t)(kc * NT + r) * D + dc * DC + dbase;
            float4 a0 = *(const float4*)(wr + 0);
            float4 a1 = *(const float4*)(wr + 4);
            float4 a2 = *(const float4*)(wr + 8);
            float4 a3 = *(const float4*)(wr + 12);

            __syncthreads();   // previous chunk's compute done before overwrite
            Ws[dbase + 0][r] = a0.x;  Ws[dbase + 1][r] = a0.y;
            Ws[dbase + 2][r] = a0.z;  Ws[dbase + 3][r] = a0.w;
            Ws[dbase + 4][r] = a1.x;  Ws[dbase + 5][r] = a1.y;
            Ws[dbase + 6][r] = a1.z;  Ws[dbase + 7][r] = a1.w;
            Ws[dbase + 8][r] = a2.x;  Ws[dbase + 9][r] = a2.y;
            Ws[dbase +10][r] = a2.z;  Ws[dbase +11][r] = a2.w;
            Ws[dbase +12][r] = a3.x;  Ws[dbase +13][r] = a3.y;
            Ws[dbase +14][r] = a3.z;  Ws[dbase +15][r] = a3.w;
            __syncthreads();

            #pragma unroll 4
            for (int d = 0; d < DC; ++d) {
                float4 xv = *(const float4*)&Xs[dc * DC + d][ty * 4];
                float4 wv = *(const float4*)&Ws[d][tx * 4];
                acc[0][0] += xv.x * wv.x;  acc[0][1] += xv.x * wv.y;
                acc[0][2] += xv.x * wv.z;  acc[0][3] += xv.x * wv.w;
                acc[1][0] += xv.y * wv.x;  acc[1][1] += xv.y * wv.y;
                acc[1][2] += xv.y * wv.z;  acc[1][3] += xv.y * wv.w;
                acc[2][0] += xv.z * wv.x;  acc[2][1] += xv.z * wv.y;
                acc[2][2] += xv.z * wv.z;  acc[2][3] += xv.z * wv.w;
                acc[3][0] += xv.w * wv.x;  acc[3][1] += xv.w * wv.y;
                acc[3][2] += xv.w * wv.z;  acc[3][3] += xv.w * wv.w;
            }
        }

        // epilogue: d = (A + B_k) - 2*acc, running argmin (first-min tiebreak)
        int p0 = ty * 4;
        int kb = kc * NT + tx * 4;
        #pragma unroll
        for (int i = 0; i < 4; ++i) {
            float a = Ash[p0 + i];
            #pragma unroll
            for (int j = 0; j < 4; ++j) {
                float t  = a + ws[WS_B + kb + j];     // fl(A + B)
                float dv = t - 2.0f * acc[i][j];      // fl(.. - 2C)
                if (dv < bestv[i]) { bestv[i] = dv; besti[i] = kb + j; }
            }
        }
    }

    // reduce across the 32 tx lanes of each half-wave
    #pragma unroll
    for (int i = 0; i < 4; ++i) {
        float v = bestv[i];
        int ix = besti[i];
        for (int m = 16; m; m >>= 1) {
            float v2 = __shfl_xor(v, m, 64);
            int   i2 = __shfl_xor(ix, m, 64);
            if (v2 < v || (v2 == v && i2 < ix)) { v = v2; ix = i2; }
        }
        if (tx == 0) out_idx[n0 + ty * 4 + i] = (float)ix;
    }
}

// ---------------- kernel 3: gather + out + commitment/codebook SSE ----------------
__global__ __launch_bounds__(256) void gather_kernel(const float* __restrict__ x,
                                                     const float* __restrict__ w,
                                                     const float* __restrict__ idxf,
                                                     float* __restrict__ out,
                                                     float* __restrict__ ws) {
    __shared__ float red[256];
    int tid = threadIdx.x;
    size_t t0 = (size_t)blockIdx.x * 256 + tid;
    const size_t total4 = OUT_ELEMS / 4;
    const size_t stride = (size_t)2048 * 256;

    float sse = 0.f;
    for (size_t e4 = t0; e4 < total4; e4 += stride) {
        size_t e = e4 * 4;
        int b  = (int)(e >> 18);           // /262144
        int c  = (int)((e >> 10) & 255);
        int hw = (int)(e & 1023);
        int n  = (b << 10) + hw;

        float4 xv = *(const float4*)(x + e);
        int k0 = (int)idxf[n + 0];
        int k1 = (int)idxf[n + 1];
        int k2 = (int)idxf[n + 2];
        int k3 = (int)idxf[n + 3];
        float w0 = w[(size_t)k0 * D + c];
        float w1 = w[(size_t)k1 * D + c];
        float w2 = w[(size_t)k2 * D + c];
        float w3 = w[(size_t)k3 * D + c];
        float d0 = w0 - xv.x, d1 = w1 - xv.y, d2 = w2 - xv.z, d3 = w3 - xv.w;
        float4 ov;
        ov.x = xv.x + d0;  ov.y = xv.y + d1;   // straight-through value, same rounding as ref
        ov.z = xv.z + d2;  ov.w = xv.w + d3;
        *(float4*)(out + e) = ov;
        sse += d0 * d0 + d1 * d1 + d2 * d2 + d3 * d3;
    }

    red[tid] = sse;
    __syncthreads();
    for (int s = 128; s > 0; s >>= 1) {
        if (tid < s) red[tid] += red[tid + s];
        __syncthreads();
    }
    if (tid == 0) atomicAdd(ws + WS_SSE_VQ, red[0]);
}

// ---------------- kernel 4: orthogonality regularizer ----------------
__global__ __launch_bounds__(256) void ortho_kernel(const float* __restrict__ w,
                                                    float* __restrict__ ws) {
    __shared__ float wi[D];
    __shared__ float wsum[4];
    int i = blockIdx.x;
    int tid = threadIdx.x;
    int lane = tid & 63;
    int wid = tid >> 6;

    if (tid < 64)
        *(float4*)&wi[tid * 4] = *(const float4*)(w + (size_t)i * D + tid * 4);
    __syncthreads();

    float inv_i = 1.0f / ws[WS_NORM + i];
    float acc = 0.f;
    for (int j = wid; j < K; j += 4) {
        float4 a = *(const float4*)(w + (size_t)j * D + lane * 4);
        float4 bq = *(const float4*)&wi[lane * 4];
        float s = a.x * bq.x + a.y * bq.y + a.z * bq.z + a.w * bq.w;
        for (int m = 32; m; m >>= 1) s += __shfl_xor(s, m, 64);
        float sij = s * inv_i * (1.0f / ws[WS_NORM + j]);
        float t = sij - (j == i ? 1.0f : 0.0f);
        acc += t * t;                    // same on all lanes
    }
    if (lane == 0) wsum[wid] = acc;
    __syncthreads();
    if (tid == 0)
        atomicAdd(ws + WS_SSE_ORTHO, wsum[0] + wsum[1] + wsum[2] + wsum[3]);
}

// ---------------- kernel 5: finalize loss ----------------
__global__ void finalize_kernel(const float* __restrict__ ws, float* __restrict__ out) {
    float loss = (1.0f + BETA) * ws[WS_SSE_VQ] / (float)OUT_ELEMS
               + ORTHO_L * sqrtf(ws[WS_SSE_ORTHO]) / ((float)K * (float)K);
    out[LOSS_OFF] = loss;
}

extern "C" void kernel_launch(void* const* d_in, const int* in_sizes, int n_in,
                              void* d_out, int out_size, void* d_ws, size_t ws_size,
                              hipStream_t stream) {
    const float* x = (const float*)d_in[0];
    const float* w = (const float*)d_in[1];
    float* out = (float*)d_out;
    float* ws  = (float*)d_ws;

    hipMemsetAsync(d_ws, 0, 2 * sizeof(float), stream);
    codes_kernel<<<K, 64, 0, stream>>>(w, ws);
    argmin_kernel<<<N_PTS / MT, 256, 0, stream>>>(x, w, ws, out + IDX_OFF);
    ortho_kernel<<<K, 256, 0, stream>>>(w, ws);
    gather_kernel<<<2048, 256, 0, stream>>>(x, w, out + IDX_OFF, out, ws);
    finalize_kernel<<<1, 1, 0, stream>>>(ws, out);
}